// Round 10
// baseline (60.822 us; speedup 1.0000x reference)
//
#include <hip/hip_runtime.h>
#include <hip/hip_bf16.h>

#define NUM_BINS 512
#define T_LEN 256
#define B_LEN 16
#define WIN 101
#define HALF 50
#define NOUT 128

typedef __attribute__((ext_vector_type(8))) short short8;
typedef __attribute__((ext_vector_type(4))) float f32x4;
typedef __attribute__((ext_vector_type(4))) int v4i;

__device__ __forceinline__ unsigned short f2bf(float f) {
    unsigned u = __float_as_uint(f);
    u += 0x7fff + ((u >> 16) & 1);   // round-to-nearest-even
    return (unsigned short)(u >> 16);
}

// ---------------- Kernel 1: one wave = one frame (zero cross-wave coupling) --
// 4096 single-wave blocks (16/CU): each wave streams its 48 KB frame
// (16 iters x 3 dwordx4, 3 KB/wave/iter contiguous) with NON-TEMPORAL loads
// (read-once stream: no L2 allocation -> no thrash of the 32 MB L2 shared
// with the atomic/return path), scatters into a wave-private parity-split
// LDS histogram (idx = bin*2 + lane&1), shfl_xor-butterfly reduces the sum
// of squares, writes one coalesced 1 KB bf16 row. + 32 tail blocks: fc_w ->
// bf16 MFMA B-fragment layout [og][ks][kg][l15][e], zero-padded to K=128.
__global__ __launch_bounds__(64) void hist_kernel(const int* __restrict__ frames,
                                                  const float* __restrict__ fc_w,
                                                  __hip_bfloat16* __restrict__ xout,
                                                  unsigned short* __restrict__ fcswz) {
    const int bid = blockIdx.x;
    const int lane = threadIdx.x;   // 0..63

    if (bid >= 4096) {
        const int base = (bid - 4096) * 512 + lane * 8;
        const int l15 = (base >> 3) & 15;
        const int kg = (base >> 7) & 3;
        const int ks = (base >> 9) & 3;
        const int og = base >> 11;
        const int o = og * 16 + l15;
        short8 v;
        #pragma unroll
        for (int e = 0; e < 8; ++e) {
            const int w = ks * 32 + kg * 8 + e;
            v[e] = (short)((w < WIN) ? f2bf(fc_w[o * WIN + w]) : (unsigned short)0);
        }
        *(short8*)(fcswz + base) = v;
        return;
    }

    __shared__ int hist[2 * NUM_BINS];   // parity-interleaved: bin*2 + (lane&1)

    {
        const int4 z = {0, 0, 0, 0};
        #pragma unroll
        for (int i = 0; i < 4; ++i)
            *(int4*)(&hist[i * 256 + lane * 4]) = z;
    }
    __syncthreads();   // single-wave: cheap; orders zeroing vs atomics

    const int par = lane & 1;
    const v4i* f4 = (const v4i*)(frames + (size_t)bid * 12288);
    #pragma unroll 4
    for (int i = 0; i < 16; ++i) {
        const int q = (i * 64 + lane) * 3;   // pixel quad: 48 contiguous bytes
        v4i a = __builtin_nontemporal_load(f4 + q + 0);
        v4i b = __builtin_nontemporal_load(f4 + q + 1);
        v4i c = __builtin_nontemporal_load(f4 + q + 2);
        atomicAdd(&hist[(((a.x >> 5) << 7) | ((a.y >> 5) << 4) | ((a.z >> 5) << 1)) | par], 1);
        atomicAdd(&hist[(((a.w >> 5) << 7) | ((b.x >> 5) << 4) | ((b.y >> 5) << 1)) | par], 1);
        atomicAdd(&hist[(((b.z >> 5) << 7) | ((b.w >> 5) << 4) | ((c.x >> 5) << 1)) | par], 1);
        atomicAdd(&hist[(((c.y >> 5) << 7) | ((c.z >> 5) << 4) | ((c.w >> 5) << 1)) | par], 1);
    }
    __syncthreads();   // drain this wave's atomics before readback

    // lane owns bins [lane*8, lane*8+8) = hist indices [lane*16, lane*16+16)
    int h[8];
    {
        const int4* hp = (const int4*)(&hist[lane * 16]);
        int4 a = hp[0], b = hp[1], c = hp[2], d = hp[3];
        h[0] = a.x + a.y; h[1] = a.z + a.w;
        h[2] = b.x + b.y; h[3] = b.z + b.w;
        h[4] = c.x + c.y; h[5] = c.z + c.w;
        h[6] = d.x + d.y; h[7] = d.z + d.w;
    }
    float ss = 0.0f;
    #pragma unroll
    for (int j = 0; j < 8; ++j) ss += (float)h[j] * (float)h[j];
    #pragma unroll
    for (int off = 1; off < 64; off <<= 1) ss += __shfl_xor(ss, off, 64);
    const float inv = 1.0f / sqrtf(ss);

    short8 v;
    #pragma unroll
    for (int j = 0; j < 8; ++j) v[j] = (short)f2bf((float)h[j] * inv);
    *(short8*)((unsigned short*)xout + (size_t)bid * NUM_BINS + lane * 8) = v;
}

// ---------------- Kernel 2: MFMA banded sim + window extract + MFMA FC -------
// grid = 256 blocks (XCD = b%8 keeps per-XCD x slice L2-hot), 512 threads.
// Phase 1: wave j computes s-tile j of the 16x128 sim band (16 MFMAs, K=512).
// Phase 2: diagonal extract win[i][w] = sim[i][i+w] -> bf16, zero-pad w>=101.
// Phase 3: wave j computes 16 FC outputs via pre-swizzled bf16 fc_w (4 MFMAs).
__global__ __launch_bounds__(512) void simfc_kernel(const unsigned short* __restrict__ x,
                                                    const unsigned short* __restrict__ fcswz,
                                                    const float* __restrict__ fc_b,
                                                    float* __restrict__ out) {
    __shared__ float sim_lds[16 * 132];
    __shared__ unsigned short win_lds[16 * 136];

    const int bid = blockIdx.x;
    const int b = bid & 15;
    const int tt = bid >> 4;
    const int t0 = tt * 16;
    const int tid = threadIdx.x;
    const int lane = tid & 63;
    const int wave = tid >> 6;   // 0..7
    const int l15 = lane & 15;
    const int kg = lane >> 4;    // k-chunk 0..3

    const unsigned short* xb = x + (size_t)b * T_LEN * NUM_BINS;

    // ---- Phase 1: s-tile `wave`: cols s = t0-50+16*wave .. +15
    {
        f32x4 acc = {0.f, 0.f, 0.f, 0.f};
        const short8 zero8 = {0, 0, 0, 0, 0, 0, 0, 0};
        const int rowA = t0 + l15;
        const int rb = t0 - HALF + 16 * wave + l15;
        const bool vv = (rb >= 0) && (rb < T_LEN);
        const int rc = min(max(rb, 0), T_LEN - 1);
        const unsigned short* pa = xb + (size_t)rowA * NUM_BINS + kg * 8;
        const unsigned short* ps = xb + (size_t)rc * NUM_BINS + kg * 8;
        #pragma unroll
        for (int ks = 0; ks < 16; ++ks) {
            short8 a  = *(const short8*)(pa + ks * 32);
            short8 bb = *(const short8*)(ps + ks * 32);
            bb = vv ? bb : zero8;
            acc = __builtin_amdgcn_mfma_f32_16x16x32_bf16(a, bb, acc, 0, 0, 0);
        }
        #pragma unroll
        for (int r = 0; r < 4; ++r)
            sim_lds[(kg * 4 + r) * 132 + wave * 16 + l15] = acc[r];
    }
    __syncthreads();

    // ---- Phase 2: windowed[i][w] = sim[i][i+w], bf16, zero-pad w>=101.
    if (tid < 256) {
        const int i = tid >> 4;
        const int w8 = (tid & 15) * 8;
        short8 v;
        #pragma unroll
        for (int e = 0; e < 8; ++e) {
            const int w = w8 + e;
            const float fv = (w < WIN) ? sim_lds[i * 132 + i + w] : 0.0f;
            v[e] = (short)f2bf(fv);
        }
        *(short8*)(&win_lds[i * 136 + w8]) = v;
    }
    __syncthreads();

    // ---- Phase 3: wave owns outputs o = wave*16 + l15, K=128 MFMA.
    {
        f32x4 o0 = {0.f, 0.f, 0.f, 0.f};
        const int o = wave * 16 + l15;
        #pragma unroll
        for (int ks = 0; ks < 4; ++ks) {
            short8 a = *(const short8*)(&win_lds[l15 * 136 + ks * 32 + kg * 8]);
            short8 b0 = *(const short8*)(fcswz + ((((wave * 4 + ks) * 4 + kg) * 16 + l15) * 8));
            o0 = __builtin_amdgcn_mfma_f32_16x16x32_bf16(a, b0, o0, 0, 0, 0);
        }
        const float bias = fc_b[o];
        float* ob = out + ((size_t)b * T_LEN + t0) * NOUT;
        #pragma unroll
        for (int r = 0; r < 4; ++r)
            ob[(kg * 4 + r) * NOUT + o] = fmaxf(o0[r] + bias, 0.0f);
    }
}

extern "C" void kernel_launch(void* const* d_in, const int* in_sizes, int n_in,
                              void* d_out, int out_size, void* d_ws, size_t ws_size,
                              hipStream_t stream) {
    const int* frames = (const int*)d_in[0];
    const float* fc_w = (const float*)d_in[1];
    const float* fc_b = (const float*)d_in[2];
    float* out = (float*)d_out;
    __hip_bfloat16* x = (__hip_bfloat16*)d_ws;                          // 4 MB
    unsigned short* fcswz = (unsigned short*)((char*)d_ws + (4 << 20)); // 32 KB

    hist_kernel<<<4096 + 32, 64, 0, stream>>>(frames, fc_w, x, fcswz);
    simfc_kernel<<<256, 512, 0, stream>>>((const unsigned short*)x, fcswz, fc_b, out);
}

// Round 11
// 43.758 us; speedup vs baseline: 1.3900x; 1.3900x over previous
//
#include <hip/hip_runtime.h>
#include <hip/hip_bf16.h>

#define NUM_BINS 512
#define T_LEN 256
#define B_LEN 16
#define WIN 101
#define HALF 50
#define NOUT 128

typedef __attribute__((ext_vector_type(8))) short short8;
typedef __attribute__((ext_vector_type(4))) float f32x4;

__device__ __forceinline__ unsigned short f2bf(float f) {
    unsigned u = __float_as_uint(f);
    u += 0x7fff + ((u >> 16) & 1);   // round-to-nearest-even
    return (unsigned short)(u >> 16);
}

// ---------------- Kernel 1: one wave = one frame (zero cross-wave coupling) --
// 4096 single-wave blocks (16/CU): each wave streams its 48 KB frame
// (16 iters x 3 dwordx4, 3 KB/wave/iter contiguous; CACHED loads — the nt
// variant cost +17 us in the R10 A/B because no-allocate defeats the quad's
// line reuse), scatters into a wave-private parity-split LDS histogram
// (idx = bin*2 + lane&1), shfl_xor-butterfly reduces the sum of squares,
// writes one coalesced 1 KB bf16 row. No block barrier ever gates the VMEM
// stream. + 32 tail blocks: fc_w -> bf16 MFMA B-fragment layout
// [og][ks][kg][l15][e], zero-padded to K=128.
__global__ __launch_bounds__(64) void hist_kernel(const int* __restrict__ frames,
                                                  const float* __restrict__ fc_w,
                                                  __hip_bfloat16* __restrict__ xout,
                                                  unsigned short* __restrict__ fcswz) {
    const int bid = blockIdx.x;
    const int lane = threadIdx.x;   // 0..63

    if (bid >= 4096) {
        const int base = (bid - 4096) * 512 + lane * 8;
        const int l15 = (base >> 3) & 15;
        const int kg = (base >> 7) & 3;
        const int ks = (base >> 9) & 3;
        const int og = base >> 11;
        const int o = og * 16 + l15;
        short8 v;
        #pragma unroll
        for (int e = 0; e < 8; ++e) {
            const int w = ks * 32 + kg * 8 + e;
            v[e] = (short)((w < WIN) ? f2bf(fc_w[o * WIN + w]) : (unsigned short)0);
        }
        *(short8*)(fcswz + base) = v;
        return;
    }

    __shared__ int hist[2 * NUM_BINS];   // parity-interleaved: bin*2 + (lane&1)

    {
        const int4 z = {0, 0, 0, 0};
        #pragma unroll
        for (int i = 0; i < 4; ++i)
            *(int4*)(&hist[i * 256 + lane * 4]) = z;
    }
    __syncthreads();   // single-wave: cheap; orders zeroing vs atomics

    const int par = lane & 1;
    const int4* f4 = (const int4*)(frames + (size_t)bid * 12288);
    #pragma unroll 4
    for (int i = 0; i < 16; ++i) {
        const int q = (i * 64 + lane) * 3;   // pixel quad: 48 contiguous bytes
        int4 a = f4[q + 0];
        int4 b = f4[q + 1];
        int4 c = f4[q + 2];
        atomicAdd(&hist[(((a.x >> 5) << 7) | ((a.y >> 5) << 4) | ((a.z >> 5) << 1)) | par], 1);
        atomicAdd(&hist[(((a.w >> 5) << 7) | ((b.x >> 5) << 4) | ((b.y >> 5) << 1)) | par], 1);
        atomicAdd(&hist[(((b.z >> 5) << 7) | ((b.w >> 5) << 4) | ((c.x >> 5) << 1)) | par], 1);
        atomicAdd(&hist[(((c.y >> 5) << 7) | ((c.z >> 5) << 4) | ((c.w >> 5) << 1)) | par], 1);
    }
    __syncthreads();   // drain this wave's atomics before readback

    // lane owns bins [lane*8, lane*8+8) = hist indices [lane*16, lane*16+16)
    int h[8];
    {
        const int4* hp = (const int4*)(&hist[lane * 16]);
        int4 a = hp[0], b = hp[1], c = hp[2], d = hp[3];
        h[0] = a.x + a.y; h[1] = a.z + a.w;
        h[2] = b.x + b.y; h[3] = b.z + b.w;
        h[4] = c.x + c.y; h[5] = c.z + c.w;
        h[6] = d.x + d.y; h[7] = d.z + d.w;
    }
    float ss = 0.0f;
    #pragma unroll
    for (int j = 0; j < 8; ++j) ss += (float)h[j] * (float)h[j];
    #pragma unroll
    for (int off = 1; off < 64; off <<= 1) ss += __shfl_xor(ss, off, 64);
    const float inv = 1.0f / sqrtf(ss);

    short8 v;
    #pragma unroll
    for (int j = 0; j < 8; ++j) v[j] = (short)f2bf((float)h[j] * inv);
    *(short8*)((unsigned short*)xout + (size_t)bid * NUM_BINS + lane * 8) = v;
}

// ---------------- Kernel 2: MFMA banded sim + window extract + MFMA FC -------
// grid = 256 blocks (XCD = b%8 keeps per-XCD x slice L2-hot), 512 threads.
// Phase 1: wave j computes s-tile j of the 16x128 sim band (16 MFMAs, K=512).
// Phase 2: diagonal extract win[i][w] = sim[i][i+w] -> bf16, zero-pad w>=101.
// Phase 3: wave j computes 16 FC outputs via pre-swizzled bf16 fc_w (4 MFMAs).
__global__ __launch_bounds__(512) void simfc_kernel(const unsigned short* __restrict__ x,
                                                    const unsigned short* __restrict__ fcswz,
                                                    const float* __restrict__ fc_b,
                                                    float* __restrict__ out) {
    __shared__ float sim_lds[16 * 132];
    __shared__ unsigned short win_lds[16 * 136];

    const int bid = blockIdx.x;
    const int b = bid & 15;
    const int tt = bid >> 4;
    const int t0 = tt * 16;
    const int tid = threadIdx.x;
    const int lane = tid & 63;
    const int wave = tid >> 6;   // 0..7
    const int l15 = lane & 15;
    const int kg = lane >> 4;    // k-chunk 0..3

    const unsigned short* xb = x + (size_t)b * T_LEN * NUM_BINS;

    // ---- Phase 1: s-tile `wave`: cols s = t0-50+16*wave .. +15
    {
        f32x4 acc = {0.f, 0.f, 0.f, 0.f};
        const short8 zero8 = {0, 0, 0, 0, 0, 0, 0, 0};
        const int rowA = t0 + l15;
        const int rb = t0 - HALF + 16 * wave + l15;
        const bool vv = (rb >= 0) && (rb < T_LEN);
        const int rc = min(max(rb, 0), T_LEN - 1);
        const unsigned short* pa = xb + (size_t)rowA * NUM_BINS + kg * 8;
        const unsigned short* ps = xb + (size_t)rc * NUM_BINS + kg * 8;
        #pragma unroll
        for (int ks = 0; ks < 16; ++ks) {
            short8 a  = *(const short8*)(pa + ks * 32);
            short8 bb = *(const short8*)(ps + ks * 32);
            bb = vv ? bb : zero8;
            acc = __builtin_amdgcn_mfma_f32_16x16x32_bf16(a, bb, acc, 0, 0, 0);
        }
        #pragma unroll
        for (int r = 0; r < 4; ++r)
            sim_lds[(kg * 4 + r) * 132 + wave * 16 + l15] = acc[r];
    }
    __syncthreads();

    // ---- Phase 2: windowed[i][w] = sim[i][i+w], bf16, zero-pad w>=101.
    if (tid < 256) {
        const int i = tid >> 4;
        const int w8 = (tid & 15) * 8;
        short8 v;
        #pragma unroll
        for (int e = 0; e < 8; ++e) {
            const int w = w8 + e;
            const float fv = (w < WIN) ? sim_lds[i * 132 + i + w] : 0.0f;
            v[e] = (short)f2bf(fv);
        }
        *(short8*)(&win_lds[i * 136 + w8]) = v;
    }
    __syncthreads();

    // ---- Phase 3: wave owns outputs o = wave*16 + l15, K=128 MFMA.
    {
        f32x4 o0 = {0.f, 0.f, 0.f, 0.f};
        const int o = wave * 16 + l15;
        #pragma unroll
        for (int ks = 0; ks < 4; ++ks) {
            short8 a = *(const short8*)(&win_lds[l15 * 136 + ks * 32 + kg * 8]);
            short8 b0 = *(const short8*)(fcswz + ((((wave * 4 + ks) * 4 + kg) * 16 + l15) * 8));
            o0 = __builtin_amdgcn_mfma_f32_16x16x32_bf16(a, b0, o0, 0, 0, 0);
        }
        const float bias = fc_b[o];
        float* ob = out + ((size_t)b * T_LEN + t0) * NOUT;
        #pragma unroll
        for (int r = 0; r < 4; ++r)
            ob[(kg * 4 + r) * NOUT + o] = fmaxf(o0[r] + bias, 0.0f);
    }
}

extern "C" void kernel_launch(void* const* d_in, const int* in_sizes, int n_in,
                              void* d_out, int out_size, void* d_ws, size_t ws_size,
                              hipStream_t stream) {
    const int* frames = (const int*)d_in[0];
    const float* fc_w = (const float*)d_in[1];
    const float* fc_b = (const float*)d_in[2];
    float* out = (float*)d_out;
    __hip_bfloat16* x = (__hip_bfloat16*)d_ws;                          // 4 MB
    unsigned short* fcswz = (unsigned short*)((char*)d_ws + (4 << 20)); // 32 KB

    hist_kernel<<<4096 + 32, 64, 0, stream>>>(frames, fc_w, x, fcswz);
    simfc_kernel<<<256, 512, 0, stream>>>((const unsigned short*)x, fcswz, fc_b, out);
}